// Round 1
// baseline (1124.391 us; speedup 1.0000x reference)
//
#include <hip/hip_runtime.h>
#include <math.h>

#define N_NODES 50000
#define N_EDGES 800000
#define DIN 128
#define DH 256
#define DOUT 64
#define NLAYERS 4

// ---------------- preprocessing ----------------

__global__ void k_init_int(int* p, int n, int val) {
  int i = blockIdx.x * blockDim.x + threadIdx.x;
  if (i < n) p[i] = val;
}

__global__ void k_count(const int* __restrict__ dst, int* __restrict__ cnt, int e) {
  int i = blockIdx.x * blockDim.x + threadIdx.x;
  if (i < e) atomicAdd(&cnt[dst[i]], 1);
}

__global__ void k_dinv(const int* __restrict__ cnt, float* __restrict__ dinv, int n) {
  int i = blockIdx.x * blockDim.x + threadIdx.x;
  if (i < n) dinv[i] = rsqrtf((float)cnt[i] + 1.0f);  // +1 = self-loop; deg>=1 always
}

// 3-phase exclusive scan over cnt -> rowptr (rowptr[0]=0, rowptr[i+1]=incl_scan(cnt)[i])
__global__ void k_scan1(const int* __restrict__ cnt, int* __restrict__ rowptr,
                        int* __restrict__ bsum, int n) {
  __shared__ int sm[256];
  int i = blockIdx.x * 256 + threadIdx.x;
  int v = (i < n) ? cnt[i] : 0;
  sm[threadIdx.x] = v;
  __syncthreads();
  for (int off = 1; off < 256; off <<= 1) {
    int t = (threadIdx.x >= off) ? sm[threadIdx.x - off] : 0;
    __syncthreads();
    sm[threadIdx.x] += t;
    __syncthreads();
  }
  if (i < n) rowptr[i + 1] = sm[threadIdx.x];
  if (threadIdx.x == 255) bsum[blockIdx.x] = sm[255];
}

__global__ void k_scan2(int* bsum, int nb) {
  __shared__ int sm[256];
  int v = (threadIdx.x < nb) ? bsum[threadIdx.x] : 0;
  sm[threadIdx.x] = v;
  __syncthreads();
  for (int off = 1; off < 256; off <<= 1) {
    int t = (threadIdx.x >= off) ? sm[threadIdx.x - off] : 0;
    __syncthreads();
    sm[threadIdx.x] += t;
    __syncthreads();
  }
  if (threadIdx.x < nb) bsum[threadIdx.x] = sm[threadIdx.x] - v;  // exclusive
}

__global__ void k_scan3(int* __restrict__ rowptr, const int* __restrict__ bsum, int n) {
  int i = blockIdx.x * 256 + threadIdx.x;
  if (i < n) rowptr[i + 1] += bsum[blockIdx.x];
  if (blockIdx.x == 0 && threadIdx.x == 0) rowptr[0] = 0;
}

__global__ void k_cursor(const int* __restrict__ rowptr, int* __restrict__ cursor, int n) {
  int i = blockIdx.x * blockDim.x + threadIdx.x;
  if (i < n) cursor[i] = rowptr[i];
}

__global__ void k_fill(const int* __restrict__ src, const int* __restrict__ dst,
                       const float* __restrict__ dinv,
                       int* __restrict__ cursor, int* __restrict__ csr_src,
                       float* __restrict__ csr_w, int e) {
  int i = blockIdx.x * blockDim.x + threadIdx.x;
  if (i < e) {
    int d = dst[i], s = src[i];
    int pos = atomicAdd(&cursor[d], 1);
    csr_src[pos] = s;
    csr_w[pos] = dinv[s] * dinv[d];
  }
}

// ---------------- f32 GEMM: C[M,N] = A[M,K] @ B[K,N] (+ bias) ----------------
// 64x64 tile, BK=16, 256 threads, 4x4 microtile. N,K multiples of 16; only M guarded.

#define BM 64
#define BN 64
#define BK 16

__global__ __launch_bounds__(256) void k_gemm(const float* __restrict__ A,
                                              const float* __restrict__ B,
                                              const float* __restrict__ bias,
                                              float* __restrict__ C,
                                              int M, int N, int K) {
  __shared__ float As[BK][BM];
  __shared__ float Bs[BK][BN];
  int tid = threadIdx.x;
  int m0 = blockIdx.x * BM;
  int n0 = blockIdx.y * BN;
  int tx = tid & 15, ty = tid >> 4;
  float acc[4][4] = {};

  int lrow = tid >> 2;       // 0..63 : A tile row
  int lk4 = (tid & 3) * 4;   // 0,4,8,12 : A tile col quad
  int brow = tid >> 4;       // 0..15 : B tile row
  int bc = (tid & 15) * 4;   // B tile col quad

  for (int k0 = 0; k0 < K; k0 += BK) {
    float4 av = make_float4(0.f, 0.f, 0.f, 0.f);
    if (m0 + lrow < M)
      av = *(const float4*)(A + (size_t)(m0 + lrow) * K + k0 + lk4);
    As[lk4 + 0][lrow] = av.x;
    As[lk4 + 1][lrow] = av.y;
    As[lk4 + 2][lrow] = av.z;
    As[lk4 + 3][lrow] = av.w;
    float4 bv = *(const float4*)(B + (size_t)(k0 + brow) * N + n0 + bc);
    *(float4*)&Bs[brow][bc] = bv;
    __syncthreads();
#pragma unroll
    for (int kk = 0; kk < BK; kk++) {
      float4 a = *(const float4*)&As[kk][ty * 4];
      float4 b = *(const float4*)&Bs[kk][tx * 4];
      float ar[4] = {a.x, a.y, a.z, a.w};
      float br[4] = {b.x, b.y, b.z, b.w};
#pragma unroll
      for (int i2 = 0; i2 < 4; i2++)
#pragma unroll
        for (int j2 = 0; j2 < 4; j2++)
          acc[i2][j2] += ar[i2] * br[j2];
    }
    __syncthreads();
  }

#pragma unroll
  for (int i2 = 0; i2 < 4; i2++) {
    int r = m0 + ty * 4 + i2;
    if (r < M) {
      int c = n0 + tx * 4;
      float4 o = make_float4(acc[i2][0], acc[i2][1], acc[i2][2], acc[i2][3]);
      if (bias) {
        o.x += bias[c + 0];
        o.y += bias[c + 1];
        o.z += bias[c + 2];
        o.w += bias[c + 3];
      }
      *(float4*)(C + (size_t)r * N + c) = o;
    }
  }
}

// ---------------- aggregation: h[i] = tanh(b + dinv[i]^2*tmp[i] + sum_e w_e*tmp[src_e]) ----
// one wave (64 lanes) per node; lane l covers features [4l, 4l+4)

__global__ void k_aggregate(const float* __restrict__ tmp,
                            const int* __restrict__ rowptr,
                            const int* __restrict__ csr_src,
                            const float* __restrict__ csr_w,
                            const float* __restrict__ dinv,
                            const float* __restrict__ bias,
                            float* __restrict__ hout, int n) {
  int wave = (int)((blockIdx.x * (size_t)blockDim.x + threadIdx.x) >> 6);
  int lane = threadIdx.x & 63;
  if (wave >= n) return;
  int i = wave;
  float w0 = dinv[i];
  w0 *= w0;
  float4 sv = ((const float4*)(tmp + (size_t)i * DH))[lane];
  float4 bv = ((const float4*)bias)[lane];
  float ax = bv.x + w0 * sv.x;
  float ay = bv.y + w0 * sv.y;
  float az = bv.z + w0 * sv.z;
  float aw = bv.w + w0 * sv.w;
  int s = rowptr[i], e = rowptr[i + 1];
  for (int j = s; j < e; j++) {
    int sp = csr_src[j];
    float w = csr_w[j];
    float4 v = ((const float4*)(tmp + (size_t)sp * DH))[lane];
    ax += w * v.x;
    ay += w * v.y;
    az += w * v.z;
    aw += w * v.w;
  }
  float4 o;
  o.x = tanhf(ax);
  o.y = tanhf(ay);
  o.z = tanhf(az);
  o.w = tanhf(aw);
  ((float4*)(hout + (size_t)i * DH))[lane] = o;
}

// ---------------- launch ----------------

extern "C" void kernel_launch(void* const* d_in, const int* in_sizes, int n_in,
                              void* d_out, int out_size, void* d_ws, size_t ws_size,
                              hipStream_t stream) {
  const float* x = (const float*)d_in[0];
  const int* eidx = (const int*)d_in[1];
  const int* esrc = eidx;              // edge_index[0]
  const int* edst = eidx + N_EDGES;    // edge_index[1]
  const float* W_emb = (const float*)d_in[2];
  const float* b_emb = (const float*)d_in[3];
  const float* W_conv = (const float*)d_in[4];
  const float* b_conv = (const float*)d_in[5];
  const float* W_out = (const float*)d_in[6];
  const float* b_out = (const float*)d_in[7];
  float* out = (float*)d_out;

  char* ws = (char*)d_ws;
  size_t off = 0;
  auto alloc = [&](size_t bytes) -> void* {
    void* p = ws + off;
    off += (bytes + 255) & ~(size_t)255;
    return p;
  };
  float* h = (float*)alloc((size_t)N_NODES * DH * 4);
  float* tmp = (float*)alloc((size_t)N_NODES * DH * 4);
  float* dinv = (float*)alloc((size_t)N_NODES * 4);
  int* cnt = (int*)alloc((size_t)N_NODES * 4);
  int* rowptr = (int*)alloc((size_t)(N_NODES + 1) * 4);
  int* cursor = (int*)alloc((size_t)N_NODES * 4);
  int* bsum = (int*)alloc((size_t)((N_NODES + 255) / 256) * 4);
  int* csr_src = (int*)alloc((size_t)N_EDGES * 4);
  float* csr_w = (float*)alloc((size_t)N_EDGES * 4);

  int nb = (N_NODES + 255) / 256;  // 196 blocks
  int eb = (N_EDGES + 255) / 256;

  k_init_int<<<nb, 256, 0, stream>>>(cnt, N_NODES, 0);
  k_count<<<eb, 256, 0, stream>>>(edst, cnt, N_EDGES);
  k_dinv<<<nb, 256, 0, stream>>>(cnt, dinv, N_NODES);
  k_scan1<<<nb, 256, 0, stream>>>(cnt, rowptr, bsum, N_NODES);
  k_scan2<<<1, 256, 0, stream>>>(bsum, nb);
  k_scan3<<<nb, 256, 0, stream>>>(rowptr, bsum, N_NODES);
  k_cursor<<<nb, 256, 0, stream>>>(rowptr, cursor, N_NODES);
  k_fill<<<eb, 256, 0, stream>>>(esrc, edst, dinv, cursor, csr_src, csr_w, N_EDGES);

  // embedding: h = x @ W_emb + b_emb
  {
    dim3 g((N_NODES + BM - 1) / BM, DH / BN);
    k_gemm<<<g, 256, 0, stream>>>(x, W_emb, b_emb, h, N_NODES, DH, DIN);
  }
  // conv layers: tmp = h @ W_conv[l]; h = tanh(agg(tmp) + b_conv[l])
  for (int l = 0; l < NLAYERS; l++) {
    dim3 g((N_NODES + BM - 1) / BM, DH / BN);
    k_gemm<<<g, 256, 0, stream>>>(h, W_conv + (size_t)l * DH * DH, nullptr, tmp,
                                  N_NODES, DH, DH);
    int aggblocks = (N_NODES * 64 + 255) / 256;
    k_aggregate<<<aggblocks, 256, 0, stream>>>(tmp, rowptr, csr_src, csr_w, dinv,
                                               b_conv + (size_t)l * DH, h, N_NODES);
  }
  // out = h @ W_out + b_out
  {
    dim3 g((N_NODES + BM - 1) / BM, DOUT / BN);
    k_gemm<<<g, 256, 0, stream>>>(h, W_out, b_out, out, N_NODES, DOUT, DH);
  }
}

// Round 2
// 767.264 us; speedup vs baseline: 1.4655x; 1.4655x over previous
//
#include <hip/hip_runtime.h>
#include <math.h>

#define N_NODES 50000
#define N_EDGES 800000
#define DIN 128
#define DH 256
#define DOUT 64
#define NLAYERS 4

typedef unsigned short u16;
typedef __attribute__((ext_vector_type(8))) short short8;
typedef __attribute__((ext_vector_type(4))) float f32x4;

__device__ inline u16 f2bf(float f) {
  unsigned int u = __float_as_uint(f);
  u += 0x7fff + ((u >> 16) & 1);  // round-to-nearest-even
  return (u16)(u >> 16);
}
__device__ inline float bf2f(u16 h) {
  return __uint_as_float(((unsigned int)h) << 16);
}

#define GLD16(gp, lp)                                                        \
  __builtin_amdgcn_global_load_lds(                                          \
      (const __attribute__((address_space(1))) void*)(const void*)(gp),      \
      (__attribute__((address_space(3))) void*)(void*)(lp), 16, 0, 0)

// ---------------- preprocessing ----------------

__global__ void k_init_int(int* p, int n, int val) {
  int i = blockIdx.x * blockDim.x + threadIdx.x;
  if (i < n) p[i] = val;
}

__global__ void k_count(const int* __restrict__ dst, int* __restrict__ cnt, int e) {
  int i = blockIdx.x * blockDim.x + threadIdx.x;
  if (i < e) atomicAdd(&cnt[dst[i]], 1);
}

__global__ void k_dinv(const int* __restrict__ cnt, float* __restrict__ dinv, int n) {
  int i = blockIdx.x * blockDim.x + threadIdx.x;
  if (i < n) dinv[i] = rsqrtf((float)cnt[i] + 1.0f);  // +1 = self-loop
}

__global__ void k_scan1(const int* __restrict__ cnt, int* __restrict__ rowptr,
                        int* __restrict__ bsum, int n) {
  __shared__ int sm[256];
  int i = blockIdx.x * 256 + threadIdx.x;
  int v = (i < n) ? cnt[i] : 0;
  sm[threadIdx.x] = v;
  __syncthreads();
  for (int off = 1; off < 256; off <<= 1) {
    int t = (threadIdx.x >= off) ? sm[threadIdx.x - off] : 0;
    __syncthreads();
    sm[threadIdx.x] += t;
    __syncthreads();
  }
  if (i < n) rowptr[i + 1] = sm[threadIdx.x];
  if (threadIdx.x == 255) bsum[blockIdx.x] = sm[255];
}

__global__ void k_scan2(int* bsum, int nb) {
  __shared__ int sm[256];
  int v = (threadIdx.x < nb) ? bsum[threadIdx.x] : 0;
  sm[threadIdx.x] = v;
  __syncthreads();
  for (int off = 1; off < 256; off <<= 1) {
    int t = (threadIdx.x >= off) ? sm[threadIdx.x - off] : 0;
    __syncthreads();
    sm[threadIdx.x] += t;
    __syncthreads();
  }
  if (threadIdx.x < nb) bsum[threadIdx.x] = sm[threadIdx.x] - v;
}

__global__ void k_scan3(int* __restrict__ rowptr, const int* __restrict__ bsum, int n) {
  int i = blockIdx.x * 256 + threadIdx.x;
  if (i < n) rowptr[i + 1] += bsum[blockIdx.x];
  if (blockIdx.x == 0 && threadIdx.x == 0) rowptr[0] = 0;
}

__global__ void k_cursor(const int* __restrict__ rowptr, int* __restrict__ cursor, int n) {
  int i = blockIdx.x * blockDim.x + threadIdx.x;
  if (i < n) cursor[i] = rowptr[i];
}

__global__ void k_fill(const int* __restrict__ src, const int* __restrict__ dst,
                       const float* __restrict__ dinv,
                       int* __restrict__ cursor, int* __restrict__ csr_src,
                       float* __restrict__ csr_w, int e) {
  int i = blockIdx.x * blockDim.x + threadIdx.x;
  if (i < e) {
    int d = dst[i], s = src[i];
    int pos = atomicAdd(&cursor[d], 1);
    csr_src[pos] = s;
    csr_w[pos] = dinv[s] * dinv[d];
  }
}

// ---------------- conversions ----------------

__global__ void k_f2bf4(const float* __restrict__ in, u16* __restrict__ out, int n4) {
  int i = blockIdx.x * 256 + threadIdx.x;
  if (i < n4) {
    float4 v = ((const float4*)in)[i];
    ushort4 o;
    o.x = f2bf(v.x); o.y = f2bf(v.y); o.z = f2bf(v.z); o.w = f2bf(v.w);
    ((ushort4*)out)[i] = o;
  }
}

// Bt[n][k] = bf16(W[k][n]);  W is [K][N] row-major
__global__ void k_bt_plain(const float* __restrict__ W, u16* __restrict__ Bt, int K, int N) {
  int i = blockIdx.x * 256 + threadIdx.x;
  if (i < K * N) {
    int n = i / K, k = i % K;
    Bt[i] = f2bf(W[k * N + n]);
  }
}

// split Bt[n][k'], k' in [0,3K): [0,K)=hi, [K,2K)=lo, [2K,3K)=hi
__global__ void k_bt_split(const float* __restrict__ W, u16* __restrict__ Bt, int K, int N) {
  int i = blockIdx.x * 256 + threadIdx.x;
  if (i < 3 * K * N) {
    int n = i / (3 * K), kp = i % (3 * K);
    int k = (kp < K) ? kp : ((kp < 2 * K) ? kp - K : kp - 2 * K);
    float w = W[k * N + n];
    u16 hi = f2bf(w);
    u16 v = hi;
    if (kp >= K && kp < 2 * K) v = f2bf(w - bf2f(hi));
    Bt[i] = v;
  }
}

// ---------------- bf16 MFMA GEMM ----------------
// C[M][N] = A[M][K']·B2[K'][N], A given as (Ahi, Alo) bf16 [M][K].
// NSPLIT=1: K'=K, A=Ahi. NSPLIT=3: K'=3K, blocks (Ahi·Bhi)+(Ahi·Blo)+(Alo·Bhi).
// Bt = B2 transposed: [N][K'] bf16. BM=128, BK=32, 4 waves; wave tile 64 x (BN/2).
// EPI 0: Cf fp32 (+bias); EPI 1: Cb bf16 (+bias).
template <int BN, int NSPLIT, int EPI>
__global__ __launch_bounds__(256) void k_gemm_mfma(
    const u16* __restrict__ Ahi, const u16* __restrict__ Alo,
    const u16* __restrict__ Bt, const float* __restrict__ bias,
    float* __restrict__ Cf, u16* __restrict__ Cb, int M, int K, int N) {
  constexpr int BM = 128, BK = 32;
  constexpr int WN = BN / 2;
  constexpr int NT = WN / 16;
  __shared__ u16 As[BM * BK];
  __shared__ u16 Bs[BN * BK];
  const int tid = threadIdx.x;
  const int w = tid >> 6, lane = tid & 63;
  const int q = lane >> 4, r = lane & 15;
  const int wm = (w >> 1) * 64, wn = (w & 1) * WN;
  const int m0 = blockIdx.x * BM, n0 = blockIdx.y * BN;
  const int Kp = NSPLIT * K;
  const int lrow = lane >> 2;       // 0..15
  const int lk = (lane & 3) * 8;    // 0,8,16,24

  f32x4 acc[4][NT];
#pragma unroll
  for (int t = 0; t < 4; t++)
#pragma unroll
    for (int u = 0; u < NT; u++) acc[t][u] = (f32x4){0.f, 0.f, 0.f, 0.f};

  for (int k0 = 0; k0 < Kp; k0 += BK) {
    const u16* Aptr;
    int ka;
    if (NSPLIT == 1) {
      Aptr = Ahi; ka = k0;
    } else {
      Aptr = (k0 < 2 * K) ? Ahi : Alo;
      ka = (k0 < K) ? k0 : ((k0 < 2 * K) ? (k0 - K) : (k0 - 2 * K));
    }
    // stage A: wave w covers rows [w*32, w*32+32), 16 rows per issue
#pragma unroll
    for (int ii = 0; ii < 2; ii++) {
      int rb = w * 32 + ii * 16;
      int grow = m0 + rb + lrow;
      if (grow > M - 1) grow = M - 1;
      const u16* gp = Aptr + (size_t)grow * K + ka + lk;
      GLD16(gp, &As[rb * BK] + (size_t)lane * 8);
    }
    // stage B: wave w covers rows [w*(BN/4), ...)
#pragma unroll
    for (int ii = 0; ii < BN / 64; ii++) {
      int rb = w * (BN / 4) + ii * 16;
      const u16* gp = Bt + (size_t)(n0 + rb + lrow) * Kp + k0 + lk;
      GLD16(gp, &Bs[rb * BK] + (size_t)lane * 8);
    }
    __syncthreads();
    short8 af[4], bfr[NT];
#pragma unroll
    for (int t = 0; t < 4; t++)
      af[t] = *(const short8*)&As[(wm + t * 16 + r) * BK + q * 8];
#pragma unroll
    for (int u = 0; u < NT; u++)
      bfr[u] = *(const short8*)&Bs[(wn + u * 16 + r) * BK + q * 8];
#pragma unroll
    for (int t = 0; t < 4; t++)
#pragma unroll
      for (int u = 0; u < NT; u++)
        acc[t][u] = __builtin_amdgcn_mfma_f32_16x16x32_bf16(af[t], bfr[u], acc[t][u], 0, 0, 0);
    __syncthreads();
  }

#pragma unroll
  for (int t = 0; t < 4; t++) {
#pragma unroll
    for (int rg = 0; rg < 4; rg++) {
      int row = m0 + wm + t * 16 + q * 4 + rg;
      if (row < M) {
#pragma unroll
        for (int u = 0; u < NT; u++) {
          int col = n0 + wn + u * 16 + r;
          float v = acc[t][u][rg];
          if (bias) v += bias[col];
          if (EPI == 0)
            Cf[(size_t)row * N + col] = v;
          else
            Cb[(size_t)row * N + col] = f2bf(v);
        }
      }
    }
  }
}

// ---------------- aggregation ----------------
// h[i] = tanh(b + dinv[i]^2*tmp[i] + sum_e w_e*tmp[src_e]); writes bf16 hi (+lo).
// BF=1: tmp is bf16; BF=0: tmp is fp32. One wave per node, lane covers 4 feats.
template <int BF>
__global__ void k_aggregate(const float* __restrict__ tmpf, const u16* __restrict__ tmpb,
                            const int* __restrict__ rowptr, const int* __restrict__ csr_src,
                            const float* __restrict__ csr_w, const float* __restrict__ dinv,
                            const float* __restrict__ bias,
                            u16* __restrict__ hi, u16* __restrict__ lo, int n) {
  int wave = (int)((blockIdx.x * (size_t)blockDim.x + threadIdx.x) >> 6);
  int lane = threadIdx.x & 63;
  if (wave >= n) return;
  int i = wave;
  float w0 = dinv[i];
  w0 *= w0;
  float4 sv, bv = ((const float4*)bias)[lane];
  if (BF) {
    ushort4 t = ((const ushort4*)tmpb)[(size_t)i * (DH / 4) + lane];
    sv = make_float4(bf2f(t.x), bf2f(t.y), bf2f(t.z), bf2f(t.w));
  } else {
    sv = ((const float4*)tmpf)[(size_t)i * (DH / 4) + lane];
  }
  float ax = bv.x + w0 * sv.x;
  float ay = bv.y + w0 * sv.y;
  float az = bv.z + w0 * sv.z;
  float aw = bv.w + w0 * sv.w;
  int s = rowptr[i], e = rowptr[i + 1];
  for (int j = s; j < e; j++) {
    int sp = csr_src[j];
    float wgt = csr_w[j];
    float4 v;
    if (BF) {
      ushort4 t = ((const ushort4*)tmpb)[(size_t)sp * (DH / 4) + lane];
      v = make_float4(bf2f(t.x), bf2f(t.y), bf2f(t.z), bf2f(t.w));
    } else {
      v = ((const float4*)tmpf)[(size_t)sp * (DH / 4) + lane];
    }
    ax += wgt * v.x;
    ay += wgt * v.y;
    az += wgt * v.z;
    aw += wgt * v.w;
  }
  float ox = tanhf(ax), oy = tanhf(ay), oz = tanhf(az), ow = tanhf(aw);
  size_t base = (size_t)i * DH + lane * 4;
  ushort4 hv;
  hv.x = f2bf(ox); hv.y = f2bf(oy); hv.z = f2bf(oz); hv.w = f2bf(ow);
  *(ushort4*)(hi + base) = hv;
  if (lo) {
    ushort4 lv;
    lv.x = f2bf(ox - bf2f(hv.x));
    lv.y = f2bf(oy - bf2f(hv.y));
    lv.z = f2bf(oz - bf2f(hv.z));
    lv.w = f2bf(ow - bf2f(hv.w));
    *(ushort4*)(lo + base) = lv;
  }
}

// ---------------- launch ----------------

extern "C" void kernel_launch(void* const* d_in, const int* in_sizes, int n_in,
                              void* d_out, int out_size, void* d_ws, size_t ws_size,
                              hipStream_t stream) {
  const float* x = (const float*)d_in[0];
  const int* eidx = (const int*)d_in[1];
  const int* esrc = eidx;
  const int* edst = eidx + N_EDGES;
  const float* W_emb = (const float*)d_in[2];
  const float* b_emb = (const float*)d_in[3];
  const float* W_conv = (const float*)d_in[4];
  const float* b_conv = (const float*)d_in[5];
  const float* W_out = (const float*)d_in[6];
  const float* b_out = (const float*)d_in[7];
  float* out = (float*)d_out;

  char* ws = (char*)d_ws;
  size_t off = 0;
  auto alloc = [&](size_t bytes) -> void* {
    void* p = ws + off;
    off += (bytes + 255) & ~(size_t)255;
    return p;
  };
  float* tmp = (float*)alloc((size_t)N_NODES * DH * 4);   // fp32 tmp (layer 3)
  u16* tmpb = (u16*)tmp;                                  // alias: bf16 tmp (layers 0-2)
  u16* h_hi = (u16*)alloc((size_t)N_NODES * DH * 2);
  u16* h_lo = (u16*)alloc((size_t)N_NODES * DH * 2);
  u16* x_bf = h_lo;  // alias: x_bf dead before h_lo first written (layer-2 agg)
  float* dinv = (float*)alloc((size_t)N_NODES * 4);
  int* cnt = (int*)alloc((size_t)N_NODES * 4);
  int* rowptr = (int*)alloc((size_t)(N_NODES + 1) * 4);
  int* cursor = (int*)alloc((size_t)N_NODES * 4);
  int* bsum = (int*)alloc((size_t)((N_NODES + 255) / 256) * 4);
  int* csr_src = (int*)alloc((size_t)N_EDGES * 4);
  float* csr_w = (float*)alloc((size_t)N_EDGES * 4);
  u16* Bt_emb = (u16*)alloc((size_t)DH * DIN * 2);
  u16* Bt_conv0 = (u16*)alloc((size_t)DH * DH * 2);
  u16* Bt_conv1 = (u16*)alloc((size_t)DH * DH * 2);
  u16* Bt_conv2 = (u16*)alloc((size_t)DH * DH * 2);
  u16* Bt_conv3 = (u16*)alloc((size_t)DH * 3 * DH * 2);
  u16* Bt_out = (u16*)alloc((size_t)DOUT * 3 * DH * 2);

  int nb = (N_NODES + 255) / 256;
  int eb = (N_EDGES + 255) / 256;

  k_init_int<<<nb, 256, 0, stream>>>(cnt, N_NODES, 0);
  k_count<<<eb, 256, 0, stream>>>(edst, cnt, N_EDGES);
  k_dinv<<<nb, 256, 0, stream>>>(cnt, dinv, N_NODES);
  k_scan1<<<nb, 256, 0, stream>>>(cnt, rowptr, bsum, N_NODES);
  k_scan2<<<1, 256, 0, stream>>>(bsum, nb);
  k_scan3<<<nb, 256, 0, stream>>>(rowptr, bsum, N_NODES);
  k_cursor<<<nb, 256, 0, stream>>>(rowptr, cursor, N_NODES);
  k_fill<<<eb, 256, 0, stream>>>(esrc, edst, dinv, cursor, csr_src, csr_w, N_EDGES);

  k_f2bf4<<<(N_NODES * DIN / 4 + 255) / 256, 256, 0, stream>>>(x, x_bf, N_NODES * DIN / 4);
  k_bt_plain<<<(DIN * DH + 255) / 256, 256, 0, stream>>>(W_emb, Bt_emb, DIN, DH);
  k_bt_plain<<<(DH * DH + 255) / 256, 256, 0, stream>>>(W_conv + 0 * DH * DH, Bt_conv0, DH, DH);
  k_bt_plain<<<(DH * DH + 255) / 256, 256, 0, stream>>>(W_conv + 1 * DH * DH, Bt_conv1, DH, DH);
  k_bt_plain<<<(DH * DH + 255) / 256, 256, 0, stream>>>(W_conv + 2 * DH * DH, Bt_conv2, DH, DH);
  k_bt_split<<<(3 * DH * DH + 255) / 256, 256, 0, stream>>>(W_conv + 3 * DH * DH, Bt_conv3, DH, DH);
  k_bt_split<<<(3 * DH * DOUT + 255) / 256, 256, 0, stream>>>(W_out, Bt_out, DH, DOUT);

  int mblocks = (N_NODES + 127) / 128;  // 391
  int aggblocks = (N_NODES * 64 + 255) / 256;
  u16* Bt_conv[3] = {Bt_conv0, Bt_conv1, Bt_conv2};

  // emb: h0 = x @ W_emb + b_emb  -> bf16 h_hi
  {
    dim3 g(mblocks, DH / 128);
    k_gemm_mfma<128, 1, 1><<<g, 256, 0, stream>>>(x_bf, nullptr, Bt_emb, b_emb,
                                                  nullptr, h_hi, N_NODES, DIN, DH);
  }
  // conv layers
  for (int l = 0; l < NLAYERS; l++) {
    dim3 g(mblocks, DH / 128);
    if (l < 3) {
      // plain bf16 GEMM -> bf16 tmp
      k_gemm_mfma<128, 1, 1><<<g, 256, 0, stream>>>(h_hi, nullptr, Bt_conv[l], nullptr,
                                                    nullptr, tmpb, N_NODES, DH, DH);
      k_aggregate<1><<<aggblocks, 256, 0, stream>>>(nullptr, tmpb, rowptr, csr_src, csr_w,
                                                    dinv, b_conv + (size_t)l * DH,
                                                    h_hi, (l >= 2) ? h_lo : nullptr, N_NODES);
    } else {
      // split GEMM (fp32-equivalent) -> fp32 tmp
      k_gemm_mfma<128, 3, 0><<<g, 256, 0, stream>>>(h_hi, h_lo, Bt_conv3, nullptr,
                                                    tmp, nullptr, N_NODES, DH, DH);
      k_aggregate<0><<<aggblocks, 256, 0, stream>>>(tmp, nullptr, rowptr, csr_src, csr_w,
                                                    dinv, b_conv + (size_t)l * DH,
                                                    h_hi, h_lo, N_NODES);
    }
  }
  // out = h4 @ W_out + b_out (split, fp32 out)
  {
    dim3 g(mblocks, 1);
    k_gemm_mfma<64, 3, 0><<<g, 256, 0, stream>>>(h_hi, h_lo, Bt_out, b_out,
                                                 out, nullptr, N_NODES, DH, DOUT);
  }
}

// Round 3
// 708.664 us; speedup vs baseline: 1.5866x; 1.0827x over previous
//
#include <hip/hip_runtime.h>
#include <math.h>

#define N_NODES 50000
#define N_EDGES 800000
#define DIN 128
#define DH 256
#define DOUT 64
#define NLAYERS 4

typedef unsigned short u16;
typedef __attribute__((ext_vector_type(8))) short short8;
typedef __attribute__((ext_vector_type(4))) float f32x4;

__device__ inline u16 f2bf(float f) {
  unsigned int u = __float_as_uint(f);
  u += 0x7fff + ((u >> 16) & 1);  // round-to-nearest-even
  return (u16)(u >> 16);
}
__device__ inline float bf2f(u16 h) {
  return __uint_as_float(((unsigned int)h) << 16);
}

#define GLD16(gp, lp)                                                        \
  __builtin_amdgcn_global_load_lds(                                          \
      (const __attribute__((address_space(1))) void*)(const void*)(gp),      \
      (__attribute__((address_space(3))) void*)(void*)(lp), 16, 0, 0)

// ---------------- preprocessing ----------------

__global__ void k_init_int(int* p, int n, int val) {
  int i = blockIdx.x * blockDim.x + threadIdx.x;
  if (i < n) p[i] = val;
}

__global__ void k_count(const int* __restrict__ dst, int* __restrict__ cnt, int e) {
  int i = blockIdx.x * blockDim.x + threadIdx.x;
  if (i < e) atomicAdd(&cnt[dst[i]], 1);
}

// scan1 + dinv fused
__global__ void k_scan1(const int* __restrict__ cnt, int* __restrict__ rowptr,
                        int* __restrict__ bsum, float* __restrict__ dinv, int n) {
  __shared__ int sm[256];
  int i = blockIdx.x * 256 + threadIdx.x;
  int v = (i < n) ? cnt[i] : 0;
  if (i < n) dinv[i] = rsqrtf((float)v + 1.0f);  // +1 = self-loop
  sm[threadIdx.x] = v;
  __syncthreads();
  for (int off = 1; off < 256; off <<= 1) {
    int t = (threadIdx.x >= off) ? sm[threadIdx.x - off] : 0;
    __syncthreads();
    sm[threadIdx.x] += t;
    __syncthreads();
  }
  if (i < n) rowptr[i + 1] = sm[threadIdx.x];
  if (threadIdx.x == 255) bsum[blockIdx.x] = sm[255];
}

__global__ void k_scan2(int* bsum, int nb) {
  __shared__ int sm[256];
  int v = (threadIdx.x < nb) ? bsum[threadIdx.x] : 0;
  sm[threadIdx.x] = v;
  __syncthreads();
  for (int off = 1; off < 256; off <<= 1) {
    int t = (threadIdx.x >= off) ? sm[threadIdx.x - off] : 0;
    __syncthreads();
    sm[threadIdx.x] += t;
    __syncthreads();
  }
  if (threadIdx.x < nb) bsum[threadIdx.x] = sm[threadIdx.x] - v;
}

// scan3 + cursor init fused
__global__ void k_scan3(int* __restrict__ rowptr, const int* __restrict__ bsum,
                        int* __restrict__ cursor, int n) {
  int i = blockIdx.x * 256 + threadIdx.x;
  if (i < n) {
    int v = rowptr[i + 1] + bsum[blockIdx.x];
    rowptr[i + 1] = v;
    if (i + 1 < n) cursor[i + 1] = v;
  }
  if (blockIdx.x == 0 && threadIdx.x == 0) {
    rowptr[0] = 0;
    cursor[0] = 0;
  }
}

__global__ void k_fill(const int* __restrict__ src, const int* __restrict__ dst,
                       const float* __restrict__ dinv,
                       int* __restrict__ cursor, int* __restrict__ csr_src,
                       float* __restrict__ csr_w, int e) {
  int i = blockIdx.x * blockDim.x + threadIdx.x;
  if (i < e) {
    int d = dst[i], s = src[i];
    int pos = atomicAdd(&cursor[d], 1);
    csr_src[pos] = s;
    csr_w[pos] = dinv[s] * dinv[d];
  }
}

// ---------------- conversions ----------------

__global__ void k_f2bf4(const float* __restrict__ in, u16* __restrict__ out, int n4) {
  int i = blockIdx.x * 256 + threadIdx.x;
  if (i < n4) {
    float4 v = ((const float4*)in)[i];
    ushort4 o;
    o.x = f2bf(v.x); o.y = f2bf(v.y); o.z = f2bf(v.z); o.w = f2bf(v.w);
    ((ushort4*)out)[i] = o;
  }
}

// Bt[n][k] = bf16(W[k][n]);  W is [K][N] row-major
__global__ void k_bt_plain(const float* __restrict__ W, u16* __restrict__ Bt, int K, int N) {
  int i = blockIdx.x * 256 + threadIdx.x;
  if (i < K * N) {
    int n = i / K, k = i % K;
    Bt[i] = f2bf(W[k * N + n]);
  }
}

// split Bt[n][k'], k' in [0,3K): [0,K)=hi, [K,2K)=lo, [2K,3K)=hi
__global__ void k_bt_split(const float* __restrict__ W, u16* __restrict__ Bt, int K, int N) {
  int i = blockIdx.x * 256 + threadIdx.x;
  if (i < 3 * K * N) {
    int n = i / (3 * K), kp = i % (3 * K);
    int k = (kp < K) ? kp : ((kp < 2 * K) ? kp - K : kp - 2 * K);
    float w = W[k * N + n];
    u16 hi = f2bf(w);
    u16 v = hi;
    if (kp >= K && kp < 2 * K) v = f2bf(w - bf2f(hi));
    Bt[i] = v;
  }
}

// ---------------- bf16 MFMA GEMM ----------------
// C[M][N] = A[M][K']·B2[K'][N], A given as (Ahi, Alo) bf16 [M][K].
// NSPLIT=1: K'=K, A=Ahi. NSPLIT=3: K'=3K, blocks (Ahi·Bhi)+(Ahi·Blo)+(Alo·Bhi).
// Bt = B2 transposed: [N][K'] bf16. BM=128, BK=32, 4 waves; wave tile 64 x (BN/2).
// LDS layout XOR-swizzled at 16B-chunk granularity: row m, slot c holds global
// chunk c ^ (m&3) ^ ((m&4)>>2) -> fragment ds_read_b128 lands max-2-way (free).
// EPI 0: Cf fp32 (+bias); EPI 1: Cb bf16 (+bias).
template <int BN, int NSPLIT, int EPI>
__global__ __launch_bounds__(256) void k_gemm_mfma(
    const u16* __restrict__ Ahi, const u16* __restrict__ Alo,
    const u16* __restrict__ Bt, const float* __restrict__ bias,
    float* __restrict__ Cf, u16* __restrict__ Cb, int M, int K, int N) {
  constexpr int BM = 128, BK = 32;
  constexpr int WN = BN / 2;
  constexpr int NT = WN / 16;
  __shared__ u16 As[BM * BK];
  __shared__ u16 Bs[BN * BK];
  const int tid = threadIdx.x;
  const int w = tid >> 6, lane = tid & 63;
  const int q = lane >> 4, r = lane & 15;
  const int wm = (w >> 1) * 64, wn = (w & 1) * WN;
  const int m0 = blockIdx.x * BM, n0 = blockIdx.y * BN;
  const int Kp = NSPLIT * K;
  const int lrow = lane >> 2;  // 0..15 : tile row within a 16-row staging issue
  // swizzled global chunk for this lane's fixed LDS slot (slot chunk = lane&3)
  const int cg = (lane & 3) ^ (lrow & 3) ^ ((lrow & 4) >> 2);
  const int lk = cg * 8;
  // fragment-read swizzle: global chunk q of row r lives at slot q ^ f(r)
  const int swz = (q ^ (r & 3) ^ ((r & 4) >> 2)) * 8;

  f32x4 acc[4][NT];
#pragma unroll
  for (int t = 0; t < 4; t++)
#pragma unroll
    for (int u = 0; u < NT; u++) acc[t][u] = (f32x4){0.f, 0.f, 0.f, 0.f};

  for (int k0 = 0; k0 < Kp; k0 += BK) {
    const u16* Aptr;
    int ka;
    if (NSPLIT == 1) {
      Aptr = Ahi; ka = k0;
    } else {
      Aptr = (k0 < 2 * K) ? Ahi : Alo;
      ka = (k0 < K) ? k0 : ((k0 < 2 * K) ? (k0 - K) : (k0 - 2 * K));
    }
    // stage A: wave w covers rows [w*32, w*32+32), 16 rows per issue
#pragma unroll
    for (int ii = 0; ii < 2; ii++) {
      int rb = w * 32 + ii * 16;
      int grow = m0 + rb + lrow;
      if (grow > M - 1) grow = M - 1;
      const u16* gp = Aptr + (size_t)grow * K + ka + lk;
      GLD16(gp, &As[rb * BK] + (size_t)lane * 8);
    }
    // stage B: wave w covers rows [w*(BN/4), ...)
#pragma unroll
    for (int ii = 0; ii < BN / 64; ii++) {
      int rb = w * (BN / 4) + ii * 16;
      const u16* gp = Bt + (size_t)(n0 + rb + lrow) * Kp + k0 + lk;
      GLD16(gp, &Bs[rb * BK] + (size_t)lane * 8);
    }
    __syncthreads();
    short8 af[4], bfr[NT];
#pragma unroll
    for (int t = 0; t < 4; t++)
      af[t] = *(const short8*)&As[(wm + t * 16 + r) * BK + swz];
#pragma unroll
    for (int u = 0; u < NT; u++)
      bfr[u] = *(const short8*)&Bs[(wn + u * 16 + r) * BK + swz];
#pragma unroll
    for (int t = 0; t < 4; t++)
#pragma unroll
      for (int u = 0; u < NT; u++)
        acc[t][u] = __builtin_amdgcn_mfma_f32_16x16x32_bf16(af[t], bfr[u], acc[t][u], 0, 0, 0);
    __syncthreads();
  }

#pragma unroll
  for (int t = 0; t < 4; t++) {
#pragma unroll
    for (int rg = 0; rg < 4; rg++) {
      int row = m0 + wm + t * 16 + q * 4 + rg;
      if (row < M) {
#pragma unroll
        for (int u = 0; u < NT; u++) {
          int col = n0 + wn + u * 16 + r;
          float v = acc[t][u][rg];
          if (bias) v += bias[col];
          if (EPI == 0)
            Cf[(size_t)row * N + col] = v;
          else
            Cb[(size_t)row * N + col] = f2bf(v);
        }
      }
    }
  }
}

// ---------------- aggregation (bf16 in) ----------------
// h[i] = tanh(b + dinv[i]^2*tmp[i] + sum_e w_e*tmp[src_e]); writes bf16 hi (+lo).
__global__ void k_aggregate(const u16* __restrict__ tmpb,
                            const int* __restrict__ rowptr, const int* __restrict__ csr_src,
                            const float* __restrict__ csr_w, const float* __restrict__ dinv,
                            const float* __restrict__ bias,
                            u16* __restrict__ hi, u16* __restrict__ lo, int n) {
  int wave = (int)((blockIdx.x * (size_t)blockDim.x + threadIdx.x) >> 6);
  int lane = threadIdx.x & 63;
  if (wave >= n) return;
  int i = wave;
  float w0 = dinv[i];
  w0 *= w0;
  float4 bv = ((const float4*)bias)[lane];
  ushort4 t0 = ((const ushort4*)tmpb)[(size_t)i * (DH / 4) + lane];
  float ax = bv.x + w0 * bf2f(t0.x);
  float ay = bv.y + w0 * bf2f(t0.y);
  float az = bv.z + w0 * bf2f(t0.z);
  float aw = bv.w + w0 * bf2f(t0.w);
  int s = rowptr[i], e = rowptr[i + 1];
  for (int j = s; j < e; j++) {
    int sp = csr_src[j];
    float wgt = csr_w[j];
    ushort4 tv = ((const ushort4*)tmpb)[(size_t)sp * (DH / 4) + lane];
    ax += wgt * bf2f(tv.x);
    ay += wgt * bf2f(tv.y);
    az += wgt * bf2f(tv.z);
    aw += wgt * bf2f(tv.w);
  }
  float ox = tanhf(ax), oy = tanhf(ay), oz = tanhf(az), ow = tanhf(aw);
  size_t base = (size_t)i * DH + lane * 4;
  ushort4 hv;
  hv.x = f2bf(ox); hv.y = f2bf(oy); hv.z = f2bf(oz); hv.w = f2bf(ow);
  *(ushort4*)(hi + base) = hv;
  if (lo) {
    ushort4 lv;
    lv.x = f2bf(ox - bf2f(hv.x));
    lv.y = f2bf(oy - bf2f(hv.y));
    lv.z = f2bf(oz - bf2f(hv.z));
    lv.w = f2bf(ow - bf2f(hv.w));
    *(ushort4*)(lo + base) = lv;
  }
}

// ---------------- launch ----------------

extern "C" void kernel_launch(void* const* d_in, const int* in_sizes, int n_in,
                              void* d_out, int out_size, void* d_ws, size_t ws_size,
                              hipStream_t stream) {
  const float* x = (const float*)d_in[0];
  const int* eidx = (const int*)d_in[1];
  const int* esrc = eidx;
  const int* edst = eidx + N_EDGES;
  const float* W_emb = (const float*)d_in[2];
  const float* b_emb = (const float*)d_in[3];
  const float* W_conv = (const float*)d_in[4];
  const float* b_conv = (const float*)d_in[5];
  const float* W_out = (const float*)d_in[6];
  const float* b_out = (const float*)d_in[7];
  float* out = (float*)d_out;

  char* ws = (char*)d_ws;
  size_t off = 0;
  auto alloc = [&](size_t bytes) -> void* {
    void* p = ws + off;
    off += (bytes + 255) & ~(size_t)255;
    return p;
  };
  u16* tmpb = (u16*)alloc((size_t)N_NODES * DH * 2);
  u16* h_hi = (u16*)alloc((size_t)N_NODES * DH * 2);
  u16* h_lo = (u16*)alloc((size_t)N_NODES * DH * 2);
  u16* x_bf = h_lo;  // alias: x_bf dead after emb GEMM; h_lo first written at layer-3 agg
  float* dinv = (float*)alloc((size_t)N_NODES * 4);
  int* cnt = (int*)alloc((size_t)N_NODES * 4);
  int* rowptr = (int*)alloc((size_t)(N_NODES + 1) * 4);
  int* cursor = (int*)alloc((size_t)N_NODES * 4);
  int* bsum = (int*)alloc((size_t)((N_NODES + 255) / 256) * 4);
  int* csr_src = (int*)alloc((size_t)N_EDGES * 4);
  float* csr_w = (float*)alloc((size_t)N_EDGES * 4);
  u16* Bt_emb = (u16*)alloc((size_t)DH * DIN * 2);
  u16* Bt_conv0 = (u16*)alloc((size_t)DH * DH * 2);
  u16* Bt_conv1 = (u16*)alloc((size_t)DH * DH * 2);
  u16* Bt_conv2 = (u16*)alloc((size_t)DH * DH * 2);
  u16* Bt_conv3 = (u16*)alloc((size_t)DH * DH * 2);
  u16* Bt_out = (u16*)alloc((size_t)DOUT * 3 * DH * 2);

  int nb = (N_NODES + 255) / 256;
  int eb = (N_EDGES + 255) / 256;

  k_init_int<<<nb, 256, 0, stream>>>(cnt, N_NODES, 0);
  k_count<<<eb, 256, 0, stream>>>(edst, cnt, N_EDGES);
  k_scan1<<<nb, 256, 0, stream>>>(cnt, rowptr, bsum, dinv, N_NODES);
  k_scan2<<<1, 256, 0, stream>>>(bsum, nb);
  k_scan3<<<nb, 256, 0, stream>>>(rowptr, bsum, cursor, N_NODES);
  k_fill<<<eb, 256, 0, stream>>>(esrc, edst, dinv, cursor, csr_src, csr_w, N_EDGES);

  k_f2bf4<<<(N_NODES * DIN / 4 + 255) / 256, 256, 0, stream>>>(x, x_bf, N_NODES * DIN / 4);
  k_bt_plain<<<(DIN * DH + 255) / 256, 256, 0, stream>>>(W_emb, Bt_emb, DIN, DH);
  k_bt_plain<<<(DH * DH + 255) / 256, 256, 0, stream>>>(W_conv + 0 * DH * DH, Bt_conv0, DH, DH);
  k_bt_plain<<<(DH * DH + 255) / 256, 256, 0, stream>>>(W_conv + 1 * DH * DH, Bt_conv1, DH, DH);
  k_bt_plain<<<(DH * DH + 255) / 256, 256, 0, stream>>>(W_conv + 2 * DH * DH, Bt_conv2, DH, DH);
  k_bt_plain<<<(DH * DH + 255) / 256, 256, 0, stream>>>(W_conv + 3 * DH * DH, Bt_conv3, DH, DH);
  k_bt_split<<<(3 * DH * DOUT + 255) / 256, 256, 0, stream>>>(W_out, Bt_out, DH, DOUT);

  int mblocks = (N_NODES + 127) / 128;  // 391
  int aggblocks = (N_NODES * 64 + 255) / 256;
  u16* Bt_conv[4] = {Bt_conv0, Bt_conv1, Bt_conv2, Bt_conv3};

  // emb: h0 = x @ W_emb + b_emb  -> bf16 h_hi
  {
    dim3 g(mblocks, DH / 128);
    k_gemm_mfma<128, 1, 1><<<g, 256, 0, stream>>>(x_bf, nullptr, Bt_emb, b_emb,
                                                  nullptr, h_hi, N_NODES, DIN, DH);
  }
  // conv layers: all plain bf16; layer 3 agg also emits h_lo for the final split GEMM
  for (int l = 0; l < NLAYERS; l++) {
    dim3 g(mblocks, DH / 128);
    k_gemm_mfma<128, 1, 1><<<g, 256, 0, stream>>>(h_hi, nullptr, Bt_conv[l], nullptr,
                                                  nullptr, tmpb, N_NODES, DH, DH);
    k_aggregate<<<aggblocks, 256, 0, stream>>>(tmpb, rowptr, csr_src, csr_w,
                                               dinv, b_conv + (size_t)l * DH,
                                               h_hi, (l == 3) ? h_lo : nullptr, N_NODES);
  }
  // out = h4 @ W_out + b_out (split, fp32 out)
  {
    dim3 g(mblocks, 1);
    k_gemm_mfma<64, 3, 0><<<g, 256, 0, stream>>>(h_hi, h_lo, Bt_out, b_out,
                                                 out, nullptr, N_NODES, DH, DOUT);
  }
}

// Round 4
// 572.059 us; speedup vs baseline: 1.9655x; 1.2388x over previous
//
#include <hip/hip_runtime.h>
#include <math.h>

#define N_NODES 50000
#define N_EDGES 800000
#define DIN 128
#define DH 256
#define DOUT 64
#define NLAYERS 4

typedef unsigned short u16;
typedef __attribute__((ext_vector_type(8))) short short8;
typedef __attribute__((ext_vector_type(4))) float f32x4;

__device__ inline u16 f2bf(float f) {
  unsigned int u = __float_as_uint(f);
  u += 0x7fff + ((u >> 16) & 1);  // round-to-nearest-even
  return (u16)(u >> 16);
}
__device__ inline float bf2f(u16 h) {
  return __uint_as_float(((unsigned int)h) << 16);
}

#define GLD16(gp, lp)                                                        \
  __builtin_amdgcn_global_load_lds(                                          \
      (const __attribute__((address_space(1))) void*)(const void*)(gp),      \
      (__attribute__((address_space(3))) void*)(void*)(lp), 16, 0, 0)

// ---------------- preprocessing ----------------

__global__ void k_count(const int* __restrict__ dst, int* __restrict__ cnt, int e) {
  int i = blockIdx.x * blockDim.x + threadIdx.x;
  if (i < e) atomicAdd(&cnt[dst[i]], 1);
}

// scan1 + dinv fused
__global__ void k_scan1(const int* __restrict__ cnt, int* __restrict__ rowptr,
                        int* __restrict__ bsum, float* __restrict__ dinv, int n) {
  __shared__ int sm[256];
  int i = blockIdx.x * 256 + threadIdx.x;
  int v = (i < n) ? cnt[i] : 0;
  if (i < n) dinv[i] = rsqrtf((float)v + 1.0f);  // +1 = self-loop
  sm[threadIdx.x] = v;
  __syncthreads();
  for (int off = 1; off < 256; off <<= 1) {
    int t = (threadIdx.x >= off) ? sm[threadIdx.x - off] : 0;
    __syncthreads();
    sm[threadIdx.x] += t;
    __syncthreads();
  }
  if (i < n) rowptr[i + 1] = sm[threadIdx.x];
  if (threadIdx.x == 255) bsum[blockIdx.x] = sm[255];
}

__global__ void k_scan2(int* bsum, int nb) {
  __shared__ int sm[256];
  int v = (threadIdx.x < nb) ? bsum[threadIdx.x] : 0;
  sm[threadIdx.x] = v;
  __syncthreads();
  for (int off = 1; off < 256; off <<= 1) {
    int t = (threadIdx.x >= off) ? sm[threadIdx.x - off] : 0;
    __syncthreads();
    sm[threadIdx.x] += t;
    __syncthreads();
  }
  if (threadIdx.x < nb) bsum[threadIdx.x] = sm[threadIdx.x] - v;
}

// scan3 + cursor init fused
__global__ void k_scan3(int* __restrict__ rowptr, const int* __restrict__ bsum,
                        int* __restrict__ cursor, int n) {
  int i = blockIdx.x * 256 + threadIdx.x;
  if (i < n) {
    int v = rowptr[i + 1] + bsum[blockIdx.x];
    rowptr[i + 1] = v;
    if (i + 1 < n) cursor[i + 1] = v;
  }
  if (blockIdx.x == 0 && threadIdx.x == 0) {
    rowptr[0] = 0;
    cursor[0] = 0;
  }
}

__global__ void k_fill(const int* __restrict__ src, const int* __restrict__ dst,
                       const float* __restrict__ dinv,
                       int* __restrict__ cursor, int2* __restrict__ csr, int e) {
  int i = blockIdx.x * blockDim.x + threadIdx.x;
  if (i < e) {
    int d = dst[i], s = src[i];
    int pos = atomicAdd(&cursor[d], 1);
    csr[pos] = make_int2(s, __float_as_int(dinv[s] * dinv[d]));
  }
}

// ---------------- conversions ----------------

__global__ void k_f2bf4(const float* __restrict__ in, u16* __restrict__ out, int n4) {
  int i = blockIdx.x * 256 + threadIdx.x;
  if (i < n4) {
    float4 v = ((const float4*)in)[i];
    ushort4 o;
    o.x = f2bf(v.x); o.y = f2bf(v.y); o.z = f2bf(v.z); o.w = f2bf(v.w);
    ((ushort4*)out)[i] = o;
  }
}

// all weight conversions in one kernel.
// Bt layouts: plain Bt[n*K + k] = bf16(W[k*N + n]); split out: [n][kp], kp<256 hi,
// 256..512 lo, 512..768 hi.
#define W_EMB_SZ (DIN * DH)            // 32768
#define W_CONV_SZ (DH * DH)            // 65536
#define W_OUT_SZ (3 * DH * DOUT)       // 49152
__global__ void k_weights(const float* __restrict__ W_emb, const float* __restrict__ W_conv,
                          const float* __restrict__ W_out, u16* __restrict__ Bt_emb,
                          u16* __restrict__ Bt_conv, u16* __restrict__ Bt_out) {
  int i = blockIdx.x * 256 + threadIdx.x;
  if (i < W_EMB_SZ) {
    int n = i >> 7, k = i & (DIN - 1);
    Bt_emb[i] = f2bf(W_emb[k * DH + n]);
  } else if (i < W_EMB_SZ + 4 * W_CONV_SZ) {
    int j = i - W_EMB_SZ;
    int l = j >> 16, jj = j & (W_CONV_SZ - 1);
    int n = jj >> 8, k = jj & (DH - 1);
    Bt_conv[j] = f2bf(W_conv[l * W_CONV_SZ + k * DH + n]);
  } else if (i < W_EMB_SZ + 4 * W_CONV_SZ + W_OUT_SZ) {
    int j = i - W_EMB_SZ - 4 * W_CONV_SZ;
    int n = j / (3 * DH), kp = j % (3 * DH);
    int k = (kp < DH) ? kp : ((kp < 2 * DH) ? kp - DH : kp - 2 * DH);
    float wv = W_out[k * DOUT + n];
    u16 hiv = f2bf(wv);
    u16 v = hiv;
    if (kp >= DH && kp < 2 * DH) v = f2bf(wv - bf2f(hiv));
    Bt_out[j] = v;
  }
}

// ---------------- bf16 MFMA GEMM ----------------
// C[M][N] = A[M][K']·B2[K'][N], A given as (Ahi, Alo) bf16 [M][K].
// NSPLIT=1: K'=K. NSPLIT=3: K'=3K, (Ahi·Bhi)+(Ahi·Blo)+(Alo·Bhi).
// Bt = B2^T [N][K'] bf16. BM=128, BK=64, 4 waves, wave tile 64 x (BN/2).
// LDS is FRAGMENT-ORDER: slot (kb, g) holds 16 rows x 32 k as 64 lane-fragments
// of 16 B -> staging (GLD16 lane*16) and fragment ds_read_b128 (lane-consecutive)
// are both conflict-free by construction.
// EPI 0: Cf fp32 (+bias); EPI 1: Cb bf16 (+bias).
template <int BN, int NSPLIT, int EPI>
__global__ __launch_bounds__(256) void k_gemm_mfma(
    const u16* __restrict__ Ahi, const u16* __restrict__ Alo,
    const u16* __restrict__ Bt, const float* __restrict__ bias,
    float* __restrict__ Cf, u16* __restrict__ Cb, int M, int K, int N) {
  constexpr int BM = 128, BK = 64;
  constexpr int WN = BN / 2;
  constexpr int NT = WN / 16;
  constexpr int BNG = BN / 16;  // B row-groups
  __shared__ u16 As[2 * 8 * 512];     // (kb, g<8, lane*8) : 16 KB
  __shared__ u16 Bs[2 * BNG * 512];   // (kb, g<BNG, lane*8)
  const int tid = threadIdx.x;
  const int w = tid >> 6, lane = tid & 63;
  const int q = lane >> 4, r = lane & 15;
  const int wmg = (w >> 1) * 4;       // A group base for this wave
  const int wng = (w & 1) * NT;       // B group base
  const int m0 = blockIdx.x * BM, n0 = blockIdx.y * BN;
  const int Kp = NSPLIT * K;
  const int srow = lane & 15;         // staging source row within group
  const int sk = (lane >> 4) * 8;     // staging source k offset

  f32x4 acc[4][NT];
#pragma unroll
  for (int t = 0; t < 4; t++)
#pragma unroll
    for (int u = 0; u < NT; u++) acc[t][u] = (f32x4){0.f, 0.f, 0.f, 0.f};

  for (int k0 = 0; k0 < Kp; k0 += BK) {
    const u16* Aptr;
    int ka;
    if (NSPLIT == 1) {
      Aptr = Ahi; ka = k0;
    } else {
      Aptr = (k0 < 2 * K) ? Ahi : Alo;
      ka = (k0 < K) ? k0 : ((k0 < 2 * K) ? (k0 - K) : (k0 - 2 * K));
    }
    // stage A: 16 slots over 4 waves x 4 issues
#pragma unroll
    for (int ii = 0; ii < 4; ii++) {
      int g = w * 2 + (ii & 1), kb = ii >> 1;
      int grow = m0 + g * 16 + srow;
      if (grow > M - 1) grow = M - 1;
      const u16* gp = Aptr + (size_t)grow * K + ka + kb * 32 + sk;
      GLD16(gp, &As[(kb * 8 + g) * 512] + (size_t)lane * 8);
    }
    // stage B: 2*BNG slots over 4 waves x (BN/32) issues
#pragma unroll
    for (int ii = 0; ii < BN / 32; ii++) {
      int g, kb;
      if (BN == 128) { g = w * 2 + (ii & 1); kb = ii >> 1; }
      else { g = w; kb = ii; }
      const u16* gp = Bt + (size_t)(n0 + g * 16 + srow) * Kp + k0 + kb * 32 + sk;
      GLD16(gp, &Bs[(kb * BNG + g) * 512] + (size_t)lane * 8);
    }
    __syncthreads();
#pragma unroll
    for (int kb = 0; kb < 2; kb++) {
      short8 af[4], bfr[NT];
#pragma unroll
      for (int t = 0; t < 4; t++)
        af[t] = *(const short8*)&As[((kb * 8 + wmg + t) * 64 + lane) * 8];
#pragma unroll
      for (int u = 0; u < NT; u++)
        bfr[u] = *(const short8*)&Bs[((kb * BNG + wng + u) * 64 + lane) * 8];
#pragma unroll
      for (int t = 0; t < 4; t++)
#pragma unroll
        for (int u = 0; u < NT; u++)
          acc[t][u] = __builtin_amdgcn_mfma_f32_16x16x32_bf16(af[t], bfr[u], acc[t][u], 0, 0, 0);
    }
    __syncthreads();
  }

#pragma unroll
  for (int t = 0; t < 4; t++) {
#pragma unroll
    for (int rg = 0; rg < 4; rg++) {
      int row = m0 + (w >> 1) * 64 + t * 16 + q * 4 + rg;
      if (row < M) {
#pragma unroll
        for (int u = 0; u < NT; u++) {
          int col = n0 + (w & 1) * WN + u * 16 + r;
          float v = acc[t][u][rg];
          if (bias) v += bias[col];
          if (EPI == 0)
            Cf[(size_t)row * N + col] = v;
          else
            Cb[(size_t)row * N + col] = f2bf(v);
        }
      }
    }
  }
}

// ---------------- aggregation (bf16 in, unroll-4 gathers) ----------------
// h[i] = tanh(b + dinv[i]^2*tmp[i] + sum_e w_e*tmp[src_e]); writes bf16 hi (+lo).
__global__ void k_aggregate(const u16* __restrict__ tmpb,
                            const int* __restrict__ rowptr, const int2* __restrict__ csr,
                            const float* __restrict__ dinv, const float* __restrict__ bias,
                            u16* __restrict__ hi, u16* __restrict__ lo, int n) {
  int i = (int)((blockIdx.x * (size_t)blockDim.x + threadIdx.x) >> 6);
  int lane = threadIdx.x & 63;
  if (i >= n) return;
  float w0 = dinv[i];
  w0 *= w0;
  const ushort4* T = (const ushort4*)tmpb;
  float4 bv = ((const float4*)bias)[lane];
  ushort4 t0 = T[(size_t)i * 64 + lane];
  float ax = bv.x + w0 * bf2f(t0.x);
  float ay = bv.y + w0 * bf2f(t0.y);
  float az = bv.z + w0 * bf2f(t0.z);
  float aw = bv.w + w0 * bf2f(t0.w);
  int s = rowptr[i], e = rowptr[i + 1];
  int j = s;
  for (; j + 4 <= e; j += 4) {
    int2 c0 = csr[j], c1 = csr[j + 1], c2 = csr[j + 2], c3 = csr[j + 3];
    ushort4 v0 = T[(size_t)c0.x * 64 + lane];
    ushort4 v1 = T[(size_t)c1.x * 64 + lane];
    ushort4 v2 = T[(size_t)c2.x * 64 + lane];
    ushort4 v3 = T[(size_t)c3.x * 64 + lane];
    float f0 = __int_as_float(c0.y), f1 = __int_as_float(c1.y);
    float f2 = __int_as_float(c2.y), f3 = __int_as_float(c3.y);
    ax += f0 * bf2f(v0.x); ay += f0 * bf2f(v0.y); az += f0 * bf2f(v0.z); aw += f0 * bf2f(v0.w);
    ax += f1 * bf2f(v1.x); ay += f1 * bf2f(v1.y); az += f1 * bf2f(v1.z); aw += f1 * bf2f(v1.w);
    ax += f2 * bf2f(v2.x); ay += f2 * bf2f(v2.y); az += f2 * bf2f(v2.z); aw += f2 * bf2f(v2.w);
    ax += f3 * bf2f(v3.x); ay += f3 * bf2f(v3.y); az += f3 * bf2f(v3.z); aw += f3 * bf2f(v3.w);
  }
  for (; j < e; j++) {
    int2 c = csr[j];
    ushort4 v = T[(size_t)c.x * 64 + lane];
    float f = __int_as_float(c.y);
    ax += f * bf2f(v.x); ay += f * bf2f(v.y); az += f * bf2f(v.z); aw += f * bf2f(v.w);
  }
  float ox = tanhf(ax), oy = tanhf(ay), oz = tanhf(az), ow = tanhf(aw);
  size_t base = (size_t)i * DH + lane * 4;
  ushort4 hv;
  hv.x = f2bf(ox); hv.y = f2bf(oy); hv.z = f2bf(oz); hv.w = f2bf(ow);
  *(ushort4*)(hi + base) = hv;
  if (lo) {
    ushort4 lv;
    lv.x = f2bf(ox - bf2f(hv.x));
    lv.y = f2bf(oy - bf2f(hv.y));
    lv.z = f2bf(oz - bf2f(hv.z));
    lv.w = f2bf(ow - bf2f(hv.w));
    *(ushort4*)(lo + base) = lv;
  }
}

// ---------------- launch ----------------

extern "C" void kernel_launch(void* const* d_in, const int* in_sizes, int n_in,
                              void* d_out, int out_size, void* d_ws, size_t ws_size,
                              hipStream_t stream) {
  const float* x = (const float*)d_in[0];
  const int* eidx = (const int*)d_in[1];
  const int* esrc = eidx;
  const int* edst = eidx + N_EDGES;
  const float* W_emb = (const float*)d_in[2];
  const float* b_emb = (const float*)d_in[3];
  const float* W_conv = (const float*)d_in[4];
  const float* b_conv = (const float*)d_in[5];
  const float* W_out = (const float*)d_in[6];
  const float* b_out = (const float*)d_in[7];
  float* out = (float*)d_out;

  char* ws = (char*)d_ws;
  size_t off = 0;
  auto alloc = [&](size_t bytes) -> void* {
    void* p = ws + off;
    off += (bytes + 255) & ~(size_t)255;
    return p;
  };
  u16* tmpb = (u16*)alloc((size_t)N_NODES * DH * 2);
  u16* h_hi = (u16*)alloc((size_t)N_NODES * DH * 2);
  u16* h_lo = (u16*)alloc((size_t)N_NODES * DH * 2);
  u16* x_bf = h_lo;  // alias: x_bf dead after emb GEMM; h_lo first written at layer-3 agg
  float* dinv = (float*)alloc((size_t)N_NODES * 4);
  int* cnt = (int*)alloc((size_t)N_NODES * 4);
  int* rowptr = (int*)alloc((size_t)(N_NODES + 1) * 4);
  int* cursor = (int*)alloc((size_t)N_NODES * 4);
  int* bsum = (int*)alloc((size_t)((N_NODES + 255) / 256) * 4);
  int2* csr = (int2*)alloc((size_t)N_EDGES * 8);
  u16* Bt_emb = (u16*)alloc((size_t)W_EMB_SZ * 2);
  u16* Bt_conv = (u16*)alloc((size_t)4 * W_CONV_SZ * 2);
  u16* Bt_out = (u16*)alloc((size_t)W_OUT_SZ * 2);

  int nb = (N_NODES + 255) / 256;
  int eb = (N_EDGES + 255) / 256;

  hipMemsetAsync(cnt, 0, (size_t)N_NODES * 4, stream);
  k_count<<<eb, 256, 0, stream>>>(edst, cnt, N_EDGES);
  k_scan1<<<nb, 256, 0, stream>>>(cnt, rowptr, bsum, dinv, N_NODES);
  k_scan2<<<1, 256, 0, stream>>>(bsum, nb);
  k_scan3<<<nb, 256, 0, stream>>>(rowptr, bsum, cursor, N_NODES);
  k_fill<<<eb, 256, 0, stream>>>(esrc, edst, dinv, cursor, csr, N_EDGES);

  k_f2bf4<<<(N_NODES * DIN / 4 + 255) / 256, 256, 0, stream>>>(x, x_bf, N_NODES * DIN / 4);
  {
    int tot = W_EMB_SZ + 4 * W_CONV_SZ + W_OUT_SZ;
    k_weights<<<(tot + 255) / 256, 256, 0, stream>>>(W_emb, W_conv, W_out,
                                                     Bt_emb, Bt_conv, Bt_out);
  }

  int mblocks = (N_NODES + 127) / 128;  // 391
  int aggblocks = (N_NODES * 64 + 255) / 256;

  // emb: h0 = x @ W_emb + b_emb  -> bf16 h_hi
  {
    dim3 g(mblocks, DH / 128);
    k_gemm_mfma<128, 1, 1><<<g, 256, 0, stream>>>(x_bf, nullptr, Bt_emb, b_emb,
                                                  nullptr, h_hi, N_NODES, DIN, DH);
  }
  // conv layers: plain bf16; layer 3 agg also emits h_lo for the final split GEMM
  for (int l = 0; l < NLAYERS; l++) {
    dim3 g(mblocks, DH / 128);
    k_gemm_mfma<128, 1, 1><<<g, 256, 0, stream>>>(h_hi, nullptr,
                                                  Bt_conv + (size_t)l * W_CONV_SZ, nullptr,
                                                  nullptr, tmpb, N_NODES, DH, DH);
    k_aggregate<<<aggblocks, 256, 0, stream>>>(tmpb, rowptr, csr, dinv,
                                               b_conv + (size_t)l * DH,
                                               h_hi, (l == 3) ? h_lo : nullptr, N_NODES);
  }
  // out = h4 @ W_out + b_out (split, fp32 out)
  {
    dim3 g(mblocks, 1);
    k_gemm_mfma<64, 3, 0><<<g, 256, 0, stream>>>(h_hi, h_lo, Bt_out, b_out,
                                                 out, nullptr, N_NODES, DH, DOUT);
  }
}